// Round 1
// baseline (296.583 us; speedup 1.0000x reference)
//
#include <hip/hip_runtime.h>
#include <math.h>

// Problem constants
#define NS      32768           // N_SAMPLES
#define M       16384           // NS/2, packed complex FFT length = 4^7
#define NEV     16
#define NB      64
#define T2      1024            // threads for FFT kernels (16 waves)

// LDS pad: break power-of-4 strides (incl. 1024/4096 from digit-reversal scatter)
__device__ __forceinline__ int ldsIdx(int i) { return i + (i >> 5) + (i >> 10); }
#define LDS_ELEMS (M + M / 32 + M / 1024)   // 16912 float2 = 135296 B < 160 KB

__device__ __forceinline__ float2 cmul(float2 a, float2 b) {
    return make_float2(a.x * b.x - a.y * b.y, a.x * b.y + a.y * b.x);
}

// reverse 7 base-4 digits (14 bits)
__device__ __forceinline__ int rev4_14(int i) {
    int r = 0;
#pragma unroll
    for (int d = 0; d < 7; ++d) { r = (r << 2) | (i & 3); i >>= 2; }
    return r;
}

// e^{-i*2*pi*k*s/NS}, s = si + sf (integer + fraction), exact integer mod
__device__ __forceinline__ float2 shift_phase(int k, int si, float sf) {
    unsigned ksi = ((unsigned)k * (unsigned)si) & (unsigned)(NS - 1);
    float total = (float)ksi + (float)k * sf;
    float f = total * (1.0f / (float)NS);
    f -= floorf(f);
    float ang = -6.28318530717958647692f * f;
    float sv, cv;
    __sincosf(ang, &sv, &cv);
    return make_float2(cv, sv);
}

// e^{-2*pi*i*k/NS}
__device__ __forceinline__ float2 wNS(int k) {
    float ang = (float)k * (-6.28318530717958647692f / (float)NS);
    float sv, cv;
    __sincosf(ang, &sv, &cv);
    return make_float2(cv, sv);
}

// cos/sin(2*pi*n/16), n = 0..3
__device__ __constant__ float R16C[4] = {1.0f, 0.92387953251128675613f,
                                         0.70710678118654752440f, 0.38268343236508977173f};
__device__ __constant__ float R16S[4] = {0.0f, 0.38268343236508977173f,
                                         0.70710678118654752440f, 0.92387953251128675613f};

// cos/sin(2*pi*t/32), t = 0..15  (rotation per +1024 step of k: e^{-2pi*i*k/NS})
__device__ __constant__ float C32[16] = {
    1.0f, 0.98078528040323044913f, 0.92387953251128675613f, 0.83146961230254523708f,
    0.70710678118654752440f, 0.55557023301960222474f, 0.38268343236508977173f,
    0.19509032201612826785f, 0.0f, -0.19509032201612826785f, -0.38268343236508977173f,
    -0.55557023301960222474f, -0.70710678118654752440f, -0.83146961230254523708f,
    -0.92387953251128675613f, -0.98078528040323044913f};
__device__ __constant__ float S32[16] = {
    0.0f, 0.19509032201612826785f, 0.38268343236508977173f, 0.55557023301960222474f,
    0.70710678118654752440f, 0.83146961230254523708f, 0.92387953251128675613f,
    0.98078528040323044913f, 1.0f, 0.98078528040323044913f, 0.92387953251128675613f,
    0.83146961230254523708f, 0.70710678118654752440f, 0.55557023301960222474f,
    0.38268343236508977173f, 0.19509032201612826785f};

// In-place radix-4 DIT FFT of M=4^7 points in LDS; input must already be
// digit-reversed, output natural order. SIGN=-1 forward, SIGN=+1 inverse
// (unscaled). Stages (0,1),(2,3),(4,5) are FUSED: each thread owns the
// 16-element set {base + l*q} (closed under both stages) and does two radix-4
// passes in registers per LDS round-trip. LDS round-trips 7->4, barriers 7->4.
// Twiddle economy: ONE sincos per stage pair (ww = e^{TP*j/(16q)}; the stage-t
// twiddle is ww^4 via two squarings). Stage 6: one base sincos, per-iteration
// rotation by the constant R16 table (angle step is exactly 2pi/16).
template <int SIGN>
__device__ void fft_lds(float2* lds, int tid) {
    const float TP = (SIGN < 0) ? -6.28318530717958647692f
                                :  6.28318530717958647692f;
#pragma unroll
    for (int tp = 0; tp < 3; ++tp) {         // stage pairs (0,1),(2,3),(4,5)
        const int t = 2 * tp;
        const int q = 1 << (2 * t);          // 1, 16, 256
        const int j = tid & (q - 1);
        const int base = ((tid >> (2 * t)) << (2 * t + 4)) + j;
        float2 x[16];
#pragma unroll
        for (int l = 0; l < 16; ++l) x[l] = lds[ldsIdx(base + l * q)];

        // ---- both stages' twiddles from ONE sincos ----
        float2 ww, w1, w2, w3;
        if (tp > 0) {
            float sv, cv;
            __sincosf(TP * (float)j / (float)(16 * q), &sv, &cv);
            ww = make_float2(cv, sv);            // stage t+1 base twiddle
            float2 s2 = cmul(ww, ww);
            w1 = cmul(s2, s2);                   // ww^4 = e^{TP*j/(4q)}
            w2 = cmul(w1, w1);
            w3 = cmul(w2, w1);
        }

        // ---- stage t: butterflies (4m..4m+3), twiddle w1^n ----
#pragma unroll
        for (int m = 0; m < 4; ++m) {
            float2 a0 = x[4 * m], a1 = x[4 * m + 1], a2 = x[4 * m + 2], a3 = x[4 * m + 3];
            if (tp > 0) { a1 = cmul(a1, w1); a2 = cmul(a2, w2); a3 = cmul(a3, w3); }
            float2 u0 = make_float2(a0.x + a2.x, a0.y + a2.y);
            float2 u1 = make_float2(a0.x - a2.x, a0.y - a2.y);
            float2 u2 = make_float2(a1.x + a3.x, a1.y + a3.y);
            float2 u3 = make_float2(a1.x - a3.x, a1.y - a3.y);
            x[4 * m]     = make_float2(u0.x + u2.x, u0.y + u2.y);
            x[4 * m + 2] = make_float2(u0.x - u2.x, u0.y - u2.y);
            if (SIGN < 0) {
                x[4 * m + 1] = make_float2(u1.x + u3.y, u1.y - u3.x);  // u1 - i*u3
                x[4 * m + 3] = make_float2(u1.x - u3.y, u1.y + u3.x);  // u1 + i*u3
            } else {
                x[4 * m + 1] = make_float2(u1.x - u3.y, u1.y + u3.x);
                x[4 * m + 3] = make_float2(u1.x + u3.y, u1.y - u3.x);
            }
        }

        // ---- stage t+1: butterflies (n, n+4, n+8, n+12), twiddle (ww*r16^n)^m ----
#pragma unroll
        for (int n = 0; n < 4; ++n) {
            float2 a0 = x[n], a1 = x[n + 4], a2 = x[n + 8], a3 = x[n + 12];
            if (!(tp == 0 && n == 0)) {
                float2 r = make_float2(R16C[n], (SIGN < 0) ? -R16S[n] : R16S[n]);
                float2 wp = (tp > 0) ? ((n > 0) ? cmul(ww, r) : ww) : r;
                float2 wp2 = cmul(wp, wp);
                float2 wp3 = cmul(wp2, wp);
                a1 = cmul(a1, wp);
                a2 = cmul(a2, wp2);
                a3 = cmul(a3, wp3);
            }
            float2 u0 = make_float2(a0.x + a2.x, a0.y + a2.y);
            float2 u1 = make_float2(a0.x - a2.x, a0.y - a2.y);
            float2 u2 = make_float2(a1.x + a3.x, a1.y + a3.y);
            float2 u3 = make_float2(a1.x - a3.x, a1.y - a3.y);
            x[n]      = make_float2(u0.x + u2.x, u0.y + u2.y);
            x[n + 8]  = make_float2(u0.x - u2.x, u0.y - u2.y);
            if (SIGN < 0) {
                x[n + 4]  = make_float2(u1.x + u3.y, u1.y - u3.x);
                x[n + 12] = make_float2(u1.x - u3.y, u1.y + u3.x);
            } else {
                x[n + 4]  = make_float2(u1.x - u3.y, u1.y + u3.x);
                x[n + 12] = make_float2(u1.x + u3.y, u1.y - u3.x);
            }
        }
#pragma unroll
        for (int l = 0; l < 16; ++l) lds[ldsIdx(base + l * q)] = x[l];
        __syncthreads();
    }

    // ---- single stage 6, q = 4096: ONE sincos + constant rotation per iter ----
    {
        const int q = 4096;
        const float c = TP / (float)(4 * q);
        float sv, cv;
        __sincosf(c * (float)tid, &sv, &cv);
        const float2 w1b = make_float2(cv, sv);   // e^{TP*tid/16384}
#pragma unroll
        for (int it = 0; it < (M / 4) / T2; ++it) {
            const int j = tid + it * T2;          // g == 0, base == j
            // e^{TP*1024*it/16384} = e^{SIGN*2pi*it/16} — constant table
            float2 w1;
            if (it == 0) w1 = w1b;
            else {
                float2 rot = make_float2(R16C[it], (SIGN < 0) ? -R16S[it] : R16S[it]);
                w1 = cmul(w1b, rot);
            }
            float2 w2 = cmul(w1, w1);
            float2 w3 = cmul(w2, w1);
            const int I0 = ldsIdx(j);
            const int I1 = ldsIdx(j + q);
            const int I2 = ldsIdx(j + 2 * q);
            const int I3 = ldsIdx(j + 3 * q);
            float2 a0 = lds[I0];
            float2 a1 = cmul(lds[I1], w1);
            float2 a2 = cmul(lds[I2], w2);
            float2 a3 = cmul(lds[I3], w3);
            float2 u0 = make_float2(a0.x + a2.x, a0.y + a2.y);
            float2 u1 = make_float2(a0.x - a2.x, a0.y - a2.y);
            float2 u2 = make_float2(a1.x + a3.x, a1.y + a3.y);
            float2 u3 = make_float2(a1.x - a3.x, a1.y - a3.y);
            lds[I0] = make_float2(u0.x + u2.x, u0.y + u2.y);
            lds[I2] = make_float2(u0.x - u2.x, u0.y - u2.y);
            if (SIGN < 0) {
                lds[I1] = make_float2(u1.x + u3.y, u1.y - u3.x);
                lds[I3] = make_float2(u1.x - u3.y, u1.y + u3.x);
            } else {
                lds[I1] = make_float2(u1.x - u3.y, u1.y + u3.x);
                lds[I3] = make_float2(u1.x + u3.y, u1.y - u3.x);
            }
        }
        __syncthreads();
    }
}

// shifts[b*16+e] = sigmoid(dot(tl[b,e,:], W) + b0) * NS
__global__ __launch_bounds__(64) void pos_kernel(const float* __restrict__ tl,
                                                 const float* __restrict__ W,
                                                 const float* __restrict__ bp,
                                                 float* __restrict__ shifts) {
    int bid = blockIdx.x;
    int t = threadIdx.x;
    const float* row = tl + (size_t)bid * 128;
    float p = row[t] * W[t] + row[t + 64] * W[t + 64];
#pragma unroll
    for (int off = 32; off > 0; off >>= 1) p += __shfl_down(p, off);
    if (t == 0) {
        float x = p + bp[0];
        float sig = 1.0f / (1.0f + expf(-x));
        shifts[bid] = sig * (float)NS;
    }
}

// Kernel A: one block per (b,e). Load stem (fused digit-reversal) -> FFT ->
// unpack rfft bins -> phase rotate -> write phased spectrum IN PLACE over the
// stem row.
// Sincos economy in the unpack: k = tid + t*1024, so
//   wNS(k)         = wNS(tid)        * e^{-2pi*i*t/32}      (constant table)
//   shift_phase(k) = shift_phase(tid)* q^t, q = shift_phase(1024)
// q^t realized as {1,q,q^2,q^3} x running base *= q^4 every 4 iters
// (depth-4 chain, no serialization, ~8 extra VGPRs).
// Spectrum layout per row (16384 float2):
//   slot[0] = (DC, Nyquist*cos(pi*s)), slot[k] = X[k]*ph[k], k=1..M-1
__global__ __launch_bounds__(T2) void fft_phase_kernel(float* __restrict__ stems,
                                                       const float* __restrict__ shifts) {
    __shared__ float2 lds[LDS_ELEMS];
    const int tid = threadIdx.x;
    const int row = blockIdx.x;

    float* rowp = stems + (size_t)row * NS;
    const float4* src = (const float4*)rowp;
#pragma unroll
    for (int it = 0; it < (M / 2) / T2; ++it) {  // 8 float4 per thread
        int i = tid + it * T2;
        float4 v = src[i];
        lds[ldsIdx(rev4_14(2 * i))]     = make_float2(v.x, v.y);
        lds[ldsIdx(rev4_14(2 * i + 1))] = make_float2(v.z, v.w);
    }
    __syncthreads();

    fft_lds<-1>(lds, tid);

    const float s = shifts[row];
    const int si = (int)floorf(s);
    const float sf = s - (float)si;
    float2* spec = (float2*)rowp;

    const float2 ph0 = shift_phase(tid, si, sf);   // e^{-i*2pi*tid*s/NS}
    const float2 w0  = wNS(tid);                   // e^{-i*2pi*tid/NS}
    const float2 q1  = shift_phase(1024, si, sf);  // e^{-i*2pi*1024*s/NS}
    const float2 q2  = cmul(q1, q1);
    const float2 q3  = cmul(q2, q1);
    const float2 q4  = cmul(q2, q2);
    float2 phb = ph0;
#pragma unroll
    for (int t = 0; t < M / T2; ++t) {
        int k = tid + (t << 10);
        float2 ph;
        switch (t & 3) {
            case 0:  ph = phb; break;
            case 1:  ph = cmul(phb, q1); break;
            case 2:  ph = cmul(phb, q2); break;
            default: ph = cmul(phb, q3); break;
        }
        if (k == 0) {
            float2 z0 = lds[ldsIdx(0)];
            float X0 = z0.x + z0.y;   // DC, phase = 1
            float XM = z0.x - z0.y;   // Nyquist (real)
            float2 phM = shift_phase(M, si, sf);
            spec[0] = make_float2(X0, XM * phM.x);  // only Re survives irfft
        } else {
            float2 Zk = lds[ldsIdx(k)];
            float2 Zr = lds[ldsIdx(M - k)];
            float2 E = make_float2(0.5f * (Zk.x + Zr.x), 0.5f * (Zk.y - Zr.y));
            float2 O = make_float2(0.5f * (Zk.y + Zr.y), -0.5f * (Zk.x - Zr.x));
            float2 w = cmul(w0, make_float2(C32[t], -S32[t]));
            float2 wo = cmul(w, O);
            float2 X = make_float2(E.x + wo.x, E.y + wo.y);
            spec[k] = cmul(X, ph);
        }
        if ((t & 3) == 3) phb = cmul(phb, q4);
    }
}

// Kernel B1: full-grid elementwise sum of the 16 phased spectra per batch.
// Writes the batch spectrum into d_out (8 MB, exactly out_size).
__global__ __launch_bounds__(256) void reduce_kernel(const float4* __restrict__ stems,
                                                     float4* __restrict__ out) {
    int gid = blockIdx.x * 256 + threadIdx.x;   // 0 .. NB*NS/4-1
    int b = gid >> 13;                           // / (NS/4)
    int i = gid & (NS / 4 - 1);
    const float4* base = stems + (size_t)b * NEV * (NS / 4) + i;
    float4 s = base[0];
#pragma unroll
    for (int e = 1; e < NEV; ++e) {
        float4 v = base[(size_t)e * (NS / 4)];
        s.x += v.x; s.y += v.y; s.z += v.z; s.w += v.w;
    }
    out[gid] = s;
}

// Kernel B2: one block per batch. Load summed spectrum from d_out (fused
// digit-reversal), build packed Z' (rev-pair in-place trick), inverse FFT,
// overwrite d_out with the real signal. Same wNS constant-rotation trick.
__global__ __launch_bounds__(T2) void inv_kernel(float* __restrict__ out) {
    __shared__ float2 lds[LDS_ELEMS];
    const int tid = threadIdx.x;
    const int b = blockIdx.x;

    const float4* src = (const float4*)(out + (size_t)b * NS);
#pragma unroll
    for (int it = 0; it < (M / 2) / T2; ++it) {  // i indexes float4 (2 slots)
        int i = tid + it * T2;
        float4 v = src[i];
        lds[ldsIdx(rev4_14(2 * i))]     = make_float2(v.x, v.y);
        lds[ldsIdx(rev4_14(2 * i + 1))] = make_float2(v.z, v.w);
    }
    __syncthreads();

    const float2 w0 = wNS(tid);
#pragma unroll
    for (int t = 0; t < (M / 2) / T2; ++t) {
        int k = tid + (t << 10);
        if (k == 0) {
            float2 a0 = lds[ldsIdx(0)];  // (sum DC, sum Nyq)
            lds[ldsIdx(0)] = make_float2(0.5f * (a0.x + a0.y), 0.5f * (a0.x - a0.y));
            int rh = ldsIdx(rev4_14(M / 2));
            float2 ah = lds[rh];
            lds[rh] = make_float2(ah.x, -ah.y);  // Z'[M/2] = conj(A[M/2])
        } else {
            int pk = ldsIdx(rev4_14(k));
            int pm = ldsIdx(rev4_14(M - k));
            float2 a = lds[pk];
            float2 bb = lds[pm];
            float2 w = cmul(w0, make_float2(C32[t], -S32[t]));
            // Z'[k] = E + i*O, E=(A[k]+conj(A[M-k]))/2, O=conj(w)*(A[k]-conj(A[M-k]))/2
            float2 E1 = make_float2(0.5f * (a.x + bb.x), 0.5f * (a.y - bb.y));
            float2 D1 = make_float2(0.5f * (a.x - bb.x), 0.5f * (a.y + bb.y));
            float2 wc = make_float2(w.x, -w.y);
            float2 O1 = cmul(wc, D1);
            float2 z1 = make_float2(E1.x - O1.y, E1.y + O1.x);
            float2 E2 = make_float2(E1.x, -E1.y);
            float2 D2 = make_float2(-D1.x, D1.y);
            float2 O2 = cmul(w, D2);
            O2 = make_float2(-O2.x, -O2.y);
            float2 z2 = make_float2(E2.x - O2.y, E2.y + O2.x);
            lds[pk] = z1;
            lds[pm] = z2;
        }
    }
    __syncthreads();

    fft_lds<1>(lds, tid);

    const float invM = 1.0f / (float)M;
    float4* dst = (float4*)(out + (size_t)b * NS);
#pragma unroll
    for (int it = 0; it < (NS / 4) / T2; ++it) {
        int i = tid + it * T2;
        float2 z0 = lds[ldsIdx(2 * i)];
        float2 z1 = lds[ldsIdx(2 * i + 1)];
        dst[i] = make_float4(z0.x * invM, z0.y * invM, z1.x * invM, z1.y * invM);
    }
}

extern "C" void kernel_launch(void* const* d_in, const int* in_sizes, int n_in,
                              void* d_out, int out_size, void* d_ws, size_t ws_size,
                              hipStream_t stream) {
    const float* time_latent = (const float*)d_in[0];
    float* stems = (float*)d_in[1];  // clobbered in place; harness restores per launch
    // d_in[2] = targets: unused by the reference output
    const float* W_pos = (const float*)d_in[3];
    const float* b_pos = (const float*)d_in[4];
    float* out = (float*)d_out;

    float* shifts = (float*)d_ws;  // 4 KB

    pos_kernel<<<NB * NEV, 64, 0, stream>>>(time_latent, W_pos, b_pos, shifts);
    fft_phase_kernel<<<NB * NEV, T2, 0, stream>>>(stems, shifts);
    reduce_kernel<<<(NB * NS / 4) / 256, 256, 0, stream>>>((const float4*)stems,
                                                           (float4*)out);
    inv_kernel<<<NB, T2, 0, stream>>>(out);
}

// Round 3
// 286.694 us; speedup vs baseline: 1.0345x; 1.0345x over previous
//
#include <hip/hip_runtime.h>
#include <math.h>

// Problem constants
#define NS      32768           // N_SAMPLES
#define M       16384           // NS/2, packed complex FFT length = 4^7
#define NEV     16
#define NB      64
#define T2      1024            // threads for FFT kernels (16 waves)

// LDS pad: break power-of-4 strides (incl. 1024/4096 from digit-reversal scatter)
__device__ __forceinline__ int ldsIdx(int i) { return i + (i >> 5) + (i >> 10); }
#define LDS_ELEMS (M + M / 32 + M / 1024)   // 16912 float2 = 135296 B < 160 KB

__device__ __forceinline__ float2 cmul(float2 a, float2 b) {
    return make_float2(a.x * b.x - a.y * b.y, a.x * b.y + a.y * b.x);
}

// reverse 7 base-4 digits (14 bits). NOTE: this is a pure BIT permutation
// (digit d bits (2d,2d+1) -> digit 6-d bits (12-2d,13-2d)), so
// rev(x|y) = rev(x)|rev(y) whenever x,y have disjoint bit support.
__device__ __forceinline__ int rev4_14(int i) {
    int r = 0;
#pragma unroll
    for (int d = 0; d < 7; ++d) { r = (r << 2) | (i & 3); i >>= 2; }
    return r;
}

// e^{-i*2*pi*k*s/NS}, s = si + sf (integer + fraction), exact integer mod
__device__ __forceinline__ float2 shift_phase(int k, int si, float sf) {
    unsigned ksi = ((unsigned)k * (unsigned)si) & (unsigned)(NS - 1);
    float total = (float)ksi + (float)k * sf;
    float f = total * (1.0f / (float)NS);
    f -= floorf(f);
    float ang = -6.28318530717958647692f * f;
    float sv, cv;
    __sincosf(ang, &sv, &cv);
    return make_float2(cv, sv);
}

// e^{-2*pi*i*k/NS}
__device__ __forceinline__ float2 wNS(int k) {
    float ang = (float)k * (-6.28318530717958647692f / (float)NS);
    float sv, cv;
    __sincosf(ang, &sv, &cv);
    return make_float2(cv, sv);
}

// cos/sin(2*pi*n/16), n = 0..3
__device__ __constant__ float R16C[4] = {1.0f, 0.92387953251128675613f,
                                         0.70710678118654752440f, 0.38268343236508977173f};
__device__ __constant__ float R16S[4] = {0.0f, 0.38268343236508977173f,
                                         0.70710678118654752440f, 0.92387953251128675613f};

// cos/sin(2*pi*t/32), t = 0..15  (rotation per +1024 step of k: e^{-2pi*i*k/NS})
__device__ __constant__ float C32[16] = {
    1.0f, 0.98078528040323044913f, 0.92387953251128675613f, 0.83146961230254523708f,
    0.70710678118654752440f, 0.55557023301960222474f, 0.38268343236508977173f,
    0.19509032201612826785f, 0.0f, -0.19509032201612826785f, -0.38268343236508977173f,
    -0.55557023301960222474f, -0.70710678118654752440f, -0.83146961230254523708f,
    -0.92387953251128675613f, -0.98078528040323044913f};
__device__ __constant__ float S32[16] = {
    0.0f, 0.19509032201612826785f, 0.38268343236508977173f, 0.55557023301960222474f,
    0.70710678118654752440f, 0.83146961230254523708f, 0.92387953251128675613f,
    0.98078528040323044913f, 1.0f, 0.98078528040323044913f, 0.92387953251128675613f,
    0.83146961230254523708f, 0.70710678118654752440f, 0.55557023301960222474f,
    0.38268343236508977173f, 0.19509032201612826785f};

// radix-4 butterfly, no twiddle, in place
template <int SIGN>
__device__ __forceinline__ void btf4(float2* a) {
    float2 a0 = a[0], a1 = a[1], a2 = a[2], a3 = a[3];
    float2 u0 = make_float2(a0.x + a2.x, a0.y + a2.y);
    float2 u1 = make_float2(a0.x - a2.x, a0.y - a2.y);
    float2 u2 = make_float2(a1.x + a3.x, a1.y + a3.y);
    float2 u3 = make_float2(a1.x - a3.x, a1.y - a3.y);
    a[0] = make_float2(u0.x + u2.x, u0.y + u2.y);
    a[2] = make_float2(u0.x - u2.x, u0.y - u2.y);
    if (SIGN < 0) {
        a[1] = make_float2(u1.x + u3.y, u1.y - u3.x);  // u1 - i*u3
        a[3] = make_float2(u1.x - u3.y, u1.y + u3.x);  // u1 + i*u3
    } else {
        a[1] = make_float2(u1.x - u3.y, u1.y + u3.x);
        a[3] = make_float2(u1.x + u3.y, u1.y - u3.x);
    }
}

// Fused: coalesced float4 load of a natural-order row -> radix-4 STAGE 0 in
// registers -> digit-reversed scatter into LDS.
// Thread owns natural pairs (2i, 2i+1), i = tid + it*1024. Bit-perm identity:
// rev(2i) = rev(2*tid) | rev(it*2048) with rev(it*2048) in {0,8,1,9,2,10,3,11}
// and rev(2i+1) = rev(2i) | 4096. The 16 owned rev-positions
// R + {0..3, 8..11} + {0,4096} are closed under stage 0 (4 groups of 4).
template <int SIGN>
__device__ __forceinline__ void load_stage0_scatter(const float4* __restrict__ src,
                                                    float2* lds, int tid) {
    const int R = rev4_14(2 * tid);
    float2 g0[4], g1[4], g2[4], g3[4];  // (A,h=0),(A,h=1),(B,h=0),(B,h=1)
#pragma unroll
    for (int it = 0; it < 8; ++it) {
        float4 v = src[tid + (it << 10)];
        int l = it >> 1;
        if ((it & 1) == 0) { g0[l] = make_float2(v.x, v.y); g1[l] = make_float2(v.z, v.w); }
        else               { g2[l] = make_float2(v.x, v.y); g3[l] = make_float2(v.z, v.w); }
    }
    btf4<SIGN>(g0); btf4<SIGN>(g1); btf4<SIGN>(g2); btf4<SIGN>(g3);
#pragma unroll
    for (int l = 0; l < 4; ++l) {
        lds[ldsIdx(R + l)]               = g0[l];
        lds[ldsIdx(R + 4096 + l)]        = g1[l];
        lds[ldsIdx(R + 8 + l)]           = g2[l];
        lds[ldsIdx(R + 8 + 4096 + l)]    = g3[l];
    }
}

// Fused stage pairs (1,2),(3,4),(5,6) of the in-place radix-4 DIT FFT
// (stage 0 already applied by load_stage0_scatter). Each thread owns the
// 16-element set {base + l*q}, q = 4^t, closed under both stages of a pair.
// ONE sincos per pair: ww = e^{TP*j/(16q)}; stage-t twiddle = ww^4.
// Stage 6 is absorbed into the (5,6) pair (the old separate stage-6 pass
// and its LDS round-trip are gone).
template <int SIGN>
__device__ void fft_pairs(float2* lds, int tid) {
    const float TP = (SIGN < 0) ? -6.28318530717958647692f
                                :  6.28318530717958647692f;
#pragma unroll
    for (int tp = 0; tp < 3; ++tp) {         // stage pairs (1,2),(3,4),(5,6)
        const int t = 2 * tp + 1;
        const int q = 1 << (2 * t);          // 4, 64, 1024
        const int j = tid & (q - 1);
        const int base = ((tid >> (2 * t)) << (2 * t + 4)) + j;
        float2 x[16];
#pragma unroll
        for (int l = 0; l < 16; ++l) x[l] = lds[ldsIdx(base + l * q)];

        float sv, cv;
        __sincosf(TP * (float)j / (float)(16 * q), &sv, &cv);
        float2 ww = make_float2(cv, sv);     // stage t+1 base twiddle
        float2 s2 = cmul(ww, ww);
        float2 w1 = cmul(s2, s2);            // ww^4 = e^{TP*j/(4q)}
        float2 w2 = cmul(w1, w1);
        float2 w3 = cmul(w2, w1);

        // ---- stage t: butterflies (4m..4m+3), twiddle w1^n ----
#pragma unroll
        for (int m = 0; m < 4; ++m) {
            float2 a0 = x[4 * m], a1 = x[4 * m + 1], a2 = x[4 * m + 2], a3 = x[4 * m + 3];
            a1 = cmul(a1, w1); a2 = cmul(a2, w2); a3 = cmul(a3, w3);
            float2 u0 = make_float2(a0.x + a2.x, a0.y + a2.y);
            float2 u1 = make_float2(a0.x - a2.x, a0.y - a2.y);
            float2 u2 = make_float2(a1.x + a3.x, a1.y + a3.y);
            float2 u3 = make_float2(a1.x - a3.x, a1.y - a3.y);
            x[4 * m]     = make_float2(u0.x + u2.x, u0.y + u2.y);
            x[4 * m + 2] = make_float2(u0.x - u2.x, u0.y - u2.y);
            if (SIGN < 0) {
                x[4 * m + 1] = make_float2(u1.x + u3.y, u1.y - u3.x);
                x[4 * m + 3] = make_float2(u1.x - u3.y, u1.y + u3.x);
            } else {
                x[4 * m + 1] = make_float2(u1.x - u3.y, u1.y + u3.x);
                x[4 * m + 3] = make_float2(u1.x + u3.y, u1.y - u3.x);
            }
        }

        // ---- stage t+1: butterflies (n, n+4, n+8, n+12), twiddle (ww*r16^n)^m ----
#pragma unroll
        for (int n = 0; n < 4; ++n) {
            float2 a0 = x[n], a1 = x[n + 4], a2 = x[n + 8], a3 = x[n + 12];
            {
                float2 r = make_float2(R16C[n], (SIGN < 0) ? -R16S[n] : R16S[n]);
                float2 wp = (n > 0) ? cmul(ww, r) : ww;
                float2 wp2 = cmul(wp, wp);
                float2 wp3 = cmul(wp2, wp);
                a1 = cmul(a1, wp);
                a2 = cmul(a2, wp2);
                a3 = cmul(a3, wp3);
            }
            float2 u0 = make_float2(a0.x + a2.x, a0.y + a2.y);
            float2 u1 = make_float2(a0.x - a2.x, a0.y - a2.y);
            float2 u2 = make_float2(a1.x + a3.x, a1.y + a3.y);
            float2 u3 = make_float2(a1.x - a3.x, a1.y - a3.y);
            x[n]      = make_float2(u0.x + u2.x, u0.y + u2.y);
            x[n + 8]  = make_float2(u0.x - u2.x, u0.y - u2.y);
            if (SIGN < 0) {
                x[n + 4]  = make_float2(u1.x + u3.y, u1.y - u3.x);
                x[n + 12] = make_float2(u1.x - u3.y, u1.y + u3.x);
            } else {
                x[n + 4]  = make_float2(u1.x - u3.y, u1.y + u3.x);
                x[n + 12] = make_float2(u1.x + u3.y, u1.y - u3.x);
            }
        }
#pragma unroll
        for (int l = 0; l < 16; ++l) lds[ldsIdx(base + l * q)] = x[l];
        __syncthreads();
    }
}

// Kernel A: one block per (b,e). Wave 0 computes the shift (pos folded in);
// all threads: fused load+stage0+scatter -> stage pairs -> unpack rfft bins
// -> phase rotate -> write phased spectrum IN PLACE over the stem row.
// Spectrum layout per row (16384 float2):
//   slot[0] = (DC, Nyquist*cos(pi*s)), slot[k] = X[k]*ph[k], k=1..M-1
__global__ __launch_bounds__(T2) void fft_phase_kernel(float* __restrict__ stems,
                                                       const float* __restrict__ tl,
                                                       const float* __restrict__ W,
                                                       const float* __restrict__ bp) {
    __shared__ float2 lds[LDS_ELEMS];
    __shared__ float sh_shift;
    const int tid = threadIdx.x;
    const int row = blockIdx.x;
    float* rowp = stems + (size_t)row * NS;

    if (tid < 64) {   // wave 0: pos = sigmoid(dot(tl,W)+b) * NS
        const float* trow = tl + (size_t)row * 128;
        float p = trow[tid] * W[tid] + trow[tid + 64] * W[tid + 64];
#pragma unroll
        for (int off = 32; off > 0; off >>= 1) p += __shfl_down(p, off);
        if (tid == 0) {
            float x = p + bp[0];
            sh_shift = (1.0f / (1.0f + expf(-x))) * (float)NS;
        }
    }

    load_stage0_scatter<-1>((const float4*)rowp, lds, tid);
    __syncthreads();
    fft_pairs<-1>(lds, tid);

    const float s = sh_shift;
    const int si = (int)floorf(s);
    const float sf = s - (float)si;
    float2* spec = (float2*)rowp;

    const float2 ph0 = shift_phase(tid, si, sf);   // e^{-i*2pi*tid*s/NS}
    const float2 w0  = wNS(tid);                   // e^{-i*2pi*tid/NS}
    const float2 q1  = shift_phase(1024, si, sf);  // e^{-i*2pi*1024*s/NS}
    const float2 q2  = cmul(q1, q1);
    const float2 q3  = cmul(q2, q1);
    const float2 q4  = cmul(q2, q2);
    float2 phb = ph0;
#pragma unroll
    for (int t = 0; t < M / T2; ++t) {
        int k = tid + (t << 10);
        float2 ph;
        switch (t & 3) {
            case 0:  ph = phb; break;
            case 1:  ph = cmul(phb, q1); break;
            case 2:  ph = cmul(phb, q2); break;
            default: ph = cmul(phb, q3); break;
        }
        if (k == 0) {
            float2 z0 = lds[ldsIdx(0)];
            float X0 = z0.x + z0.y;   // DC, phase = 1
            float XM = z0.x - z0.y;   // Nyquist (real)
            float2 phM = shift_phase(M, si, sf);
            spec[0] = make_float2(X0, XM * phM.x);  // only Re survives irfft
        } else {
            float2 Zk = lds[ldsIdx(k)];
            float2 Zr = lds[ldsIdx(M - k)];
            float2 E = make_float2(0.5f * (Zk.x + Zr.x), 0.5f * (Zk.y - Zr.y));
            float2 O = make_float2(0.5f * (Zk.y + Zr.y), -0.5f * (Zk.x - Zr.x));
            float2 w = cmul(w0, make_float2(C32[t], -S32[t]));
            float2 wo = cmul(w, O);
            float2 X = make_float2(E.x + wo.x, E.y + wo.y);
            spec[k] = cmul(X, ph);
        }
        if ((t & 3) == 3) phb = cmul(phb, q4);
    }
}

// z-pair for the inverse repack: given summed A[k] (=a), A[M-k] (=bb) and
// w = e^{-2pi*i*k/NS}, produce Z'[k] (=z1) and Z'[M-k] (=z2).
__device__ __forceinline__ void zpair(float2 a, float2 bb, float2 w,
                                      float2* z1, float2* z2) {
    float2 E1 = make_float2(0.5f * (a.x + bb.x), 0.5f * (a.y - bb.y));
    float2 D1 = make_float2(0.5f * (a.x - bb.x), 0.5f * (a.y + bb.y));
    float2 O1 = cmul(make_float2(w.x, -w.y), D1);
    *z1 = make_float2(E1.x - O1.y, E1.y + O1.x);          // E1 + i*O1
    float2 D2 = make_float2(-D1.x, D1.y);                  // -conj(D1)
    float2 O2p = cmul(w, D2);                              // O2 = -O2p
    *z2 = make_float2(E1.x + O2p.y, -E1.y - O2p.x);        // conj(E1) + i*O2
}

// Kernel B: fused reduce + repack. Full grid; thread (b,i) sums the 16 phased
// spectra at slots {2i, 2i+1} AND their conjugate partners {M-2i-1, M-2i},
// builds the packed Z' entries, writes them in NATURAL order into d_out.
// (inv_kernel then needs no repack pass.) Same 128 MB HBM read as the old
// elementwise reduce. i==0 handles DC/Nyquist slot 0 and self-paired M/2.
__global__ __launch_bounds__(256) void reduce_repack(const float* __restrict__ stems,
                                                     float* __restrict__ out) {
    int gid = blockIdx.x * 256 + threadIdx.x;   // NB*(M/4) threads
    int b = gid >> 12;                           // / (M/4 = 4096)
    int i = gid & 4095;
    const float* brow = stems + (size_t)b * NEV * NS;
    float4 sA = make_float4(0.f, 0.f, 0.f, 0.f);
    float2 sP1 = make_float2(0.f, 0.f);
    float2 sP2 = make_float2(0.f, 0.f);
    float2 sH  = make_float2(0.f, 0.f);
#pragma unroll
    for (int e = 0; e < NEV; ++e) {
        const float* rp = brow + (size_t)e * NS;
        float4 va = ((const float4*)rp)[i];              // slots 2i, 2i+1
        sA.x += va.x; sA.y += va.y; sA.z += va.z; sA.w += va.w;
        if (i) {
            float2 p1 = ((const float2*)rp)[M - 2 * i - 1];
            float2 p2 = ((const float2*)rp)[M - 2 * i];
            sP1.x += p1.x; sP1.y += p1.y;
            sP2.x += p2.x; sP2.y += p2.y;
        } else {
            float2 p1 = ((const float2*)rp)[M - 1];      // partner of k=1
            float2 h  = ((const float2*)rp)[M / 2];      // self-paired slot
            sP1.x += p1.x; sP1.y += p1.y;
            sH.x  += h.x;  sH.y  += h.y;
        }
    }
    float* orow = out + (size_t)b * NS;
    float2* o2 = (float2*)orow;
    if (i) {
        int k = 2 * i;
        float2 z1a, z2a, z1b, z2b;
        zpair(make_float2(sA.x, sA.y), sP2, wNS(k),     &z1a, &z2a);
        zpair(make_float2(sA.z, sA.w), sP1, wNS(k + 1), &z1b, &z2b);
        ((float4*)orow)[i] = make_float4(z1a.x, z1a.y, z1b.x, z1b.y);
        o2[M - k]     = z2a;
        o2[M - k - 1] = z2b;
    } else {
        float2 z0 = make_float2(0.5f * (sA.x + sA.y), 0.5f * (sA.x - sA.y));
        float2 z1b, z2b;
        zpair(make_float2(sA.z, sA.w), sP1, wNS(1), &z1b, &z2b);
        ((float4*)orow)[0] = make_float4(z0.x, z0.y, z1b.x, z1b.y);
        o2[M - 1] = z2b;
        o2[M / 2] = make_float2(sH.x, -sH.y);   // Z'[M/2] = conj(A[M/2])
    }
}

// Kernel C: one block per batch. Z' is already packed & natural-order in
// d_out: fused load+stage0+scatter -> inverse stage pairs -> scaled real write.
__global__ __launch_bounds__(T2) void inv_kernel(float* __restrict__ out) {
    __shared__ float2 lds[LDS_ELEMS];
    const int tid = threadIdx.x;
    const int b = blockIdx.x;
    float* rowp = out + (size_t)b * NS;

    load_stage0_scatter<1>((const float4*)rowp, lds, tid);
    __syncthreads();
    fft_pairs<1>(lds, tid);

    const float invM = 1.0f / (float)M;
    float4* dst = (float4*)rowp;
#pragma unroll
    for (int it = 0; it < (NS / 4) / T2; ++it) {
        int i = tid + it * T2;
        float2 z0 = lds[ldsIdx(2 * i)];
        float2 z1 = lds[ldsIdx(2 * i + 1)];
        dst[i] = make_float4(z0.x * invM, z0.y * invM, z1.x * invM, z1.y * invM);
    }
}

extern "C" void kernel_launch(void* const* d_in, const int* in_sizes, int n_in,
                              void* d_out, int out_size, void* d_ws, size_t ws_size,
                              hipStream_t stream) {
    const float* time_latent = (const float*)d_in[0];
    float* stems = (float*)d_in[1];  // clobbered in place; harness restores per launch
    // d_in[2] = targets: unused by the reference output
    const float* W_pos = (const float*)d_in[3];
    const float* b_pos = (const float*)d_in[4];
    float* out = (float*)d_out;

    fft_phase_kernel<<<NB * NEV, T2, 0, stream>>>(stems, time_latent, W_pos, b_pos);
    reduce_repack<<<(NB * (M / 4)) / 256, 256, 0, stream>>>(stems, out);
    inv_kernel<<<NB, T2, 0, stream>>>(out);
}

// Round 4
// 284.681 us; speedup vs baseline: 1.0418x; 1.0071x over previous
//
#include <hip/hip_runtime.h>
#include <math.h>

// Problem constants
#define NS      32768           // N_SAMPLES
#define M       16384           // NS/2, packed complex FFT length = 4^7
#define NEV     16
#define NB      64
#define T2      1024            // threads for FFT kernels (16 waves)

// LDS pad: break power-of-4 strides (incl. 1024/4096 from digit-reversal scatter)
__device__ __forceinline__ int ldsIdx(int i) { return i + (i >> 5) + (i >> 10); }
#define LDS_ELEMS (M + M / 32 + M / 1024)   // 16912 float2 = 135296 B < 160 KB

__device__ __forceinline__ float2 cmul(float2 a, float2 b) {
    return make_float2(a.x * b.x - a.y * b.y, a.x * b.y + a.y * b.x);
}

// reverse 7 base-4 digits (14 bits). Pure BIT permutation: rev(x|y)=rev(x)|rev(y)
// for disjoint bit support.
__device__ __forceinline__ int rev4_14(int i) {
    int r = 0;
#pragma unroll
    for (int d = 0; d < 7; ++d) { r = (r << 2) | (i & 3); i >>= 2; }
    return r;
}

// e^{-i*2*pi*k*s/NS}, s = si + sf (integer + fraction), exact integer mod
__device__ __forceinline__ float2 shift_phase(int k, int si, float sf) {
    unsigned ksi = ((unsigned)k * (unsigned)si) & (unsigned)(NS - 1);
    float total = (float)ksi + (float)k * sf;
    float f = total * (1.0f / (float)NS);
    f -= floorf(f);
    float ang = -6.28318530717958647692f * f;
    float sv, cv;
    __sincosf(ang, &sv, &cv);
    return make_float2(cv, sv);
}

// e^{-2*pi*i*k/NS}
__device__ __forceinline__ float2 wNS(int k) {
    float ang = (float)k * (-6.28318530717958647692f / (float)NS);
    float sv, cv;
    __sincosf(ang, &sv, &cv);
    return make_float2(cv, sv);
}

// cos/sin(2*pi*n/16), n = 0..3
__device__ __constant__ float R16C[4] = {1.0f, 0.92387953251128675613f,
                                         0.70710678118654752440f, 0.38268343236508977173f};
__device__ __constant__ float R16S[4] = {0.0f, 0.38268343236508977173f,
                                         0.70710678118654752440f, 0.92387953251128675613f};

// cos/sin(2*pi*t/32), t = 0..15  (rotation per +1024 step of k: e^{-2pi*i*k/NS})
__device__ __constant__ float C32[16] = {
    1.0f, 0.98078528040323044913f, 0.92387953251128675613f, 0.83146961230254523708f,
    0.70710678118654752440f, 0.55557023301960222474f, 0.38268343236508977173f,
    0.19509032201612826785f, 0.0f, -0.19509032201612826785f, -0.38268343236508977173f,
    -0.55557023301960222474f, -0.70710678118654752440f, -0.83146961230254523708f,
    -0.92387953251128675613f, -0.98078528040323044913f};
__device__ __constant__ float S32[16] = {
    0.0f, 0.19509032201612826785f, 0.38268343236508977173f, 0.55557023301960222474f,
    0.70710678118654752440f, 0.83146961230254523708f, 0.92387953251128675613f,
    0.98078528040323044913f, 1.0f, 0.98078528040323044913f, 0.92387953251128675613f,
    0.83146961230254523708f, 0.70710678118654752440f, 0.55557023301960222474f,
    0.38268343236508977173f, 0.19509032201612826785f};

// radix-4 butterfly, no twiddle, in place
template <int SIGN>
__device__ __forceinline__ void btf4(float2* a) {
    float2 a0 = a[0], a1 = a[1], a2 = a[2], a3 = a[3];
    float2 u0 = make_float2(a0.x + a2.x, a0.y + a2.y);
    float2 u1 = make_float2(a0.x - a2.x, a0.y - a2.y);
    float2 u2 = make_float2(a1.x + a3.x, a1.y + a3.y);
    float2 u3 = make_float2(a1.x - a3.x, a1.y - a3.y);
    a[0] = make_float2(u0.x + u2.x, u0.y + u2.y);
    a[2] = make_float2(u0.x - u2.x, u0.y - u2.y);
    if (SIGN < 0) {
        a[1] = make_float2(u1.x + u3.y, u1.y - u3.x);  // u1 - i*u3
        a[3] = make_float2(u1.x - u3.y, u1.y + u3.x);  // u1 + i*u3
    } else {
        a[1] = make_float2(u1.x - u3.y, u1.y + u3.x);
        a[3] = make_float2(u1.x + u3.y, u1.y - u3.x);
    }
}

// Fused: coalesced float4 load of a natural-order row -> radix-4 STAGE 0 in
// registers -> digit-reversed scatter into LDS.
// rev(2i) = rev(2*tid) | rev(it*2048), rev(it*2048) in {0,8,1,9,2,10,3,11},
// rev(2i+1) = rev(2i) | 4096. The 16 rev-positions R + {0..3,8..11} + {0,4096}
// are closed under stage 0 (4 groups of 4).
template <int SIGN>
__device__ __forceinline__ void load_stage0_scatter(const float4* __restrict__ src,
                                                    float2* lds, int tid) {
    const int R = rev4_14(2 * tid);
    float2 g0[4], g1[4], g2[4], g3[4];  // (A,h=0),(A,h=1),(B,h=0),(B,h=1)
#pragma unroll
    for (int it = 0; it < 8; ++it) {
        float4 v = src[tid + (it << 10)];
        int l = it >> 1;
        if ((it & 1) == 0) { g0[l] = make_float2(v.x, v.y); g1[l] = make_float2(v.z, v.w); }
        else               { g2[l] = make_float2(v.x, v.y); g3[l] = make_float2(v.z, v.w); }
    }
    btf4<SIGN>(g0); btf4<SIGN>(g1); btf4<SIGN>(g2); btf4<SIGN>(g3);
#pragma unroll
    for (int l = 0; l < 4; ++l) {
        lds[ldsIdx(R + l)]               = g0[l];
        lds[ldsIdx(R + 4096 + l)]        = g1[l];
        lds[ldsIdx(R + 8 + l)]           = g2[l];
        lds[ldsIdx(R + 8 + 4096 + l)]    = g3[l];
    }
}

// Fused stage pairs (1,2),(3,4),(5,6) (stage 0 done in registers at load).
// ONE sincos per pair: ww = e^{TP*j/(16q)}; stage-t twiddle = ww^4.
template <int SIGN>
__device__ void fft_pairs(float2* lds, int tid) {
    const float TP = (SIGN < 0) ? -6.28318530717958647692f
                                :  6.28318530717958647692f;
#pragma unroll
    for (int tp = 0; tp < 3; ++tp) {         // stage pairs (1,2),(3,4),(5,6)
        const int t = 2 * tp + 1;
        const int q = 1 << (2 * t);          // 4, 64, 1024
        const int j = tid & (q - 1);
        const int base = ((tid >> (2 * t)) << (2 * t + 4)) + j;
        float2 x[16];
#pragma unroll
        for (int l = 0; l < 16; ++l) x[l] = lds[ldsIdx(base + l * q)];

        float sv, cv;
        __sincosf(TP * (float)j / (float)(16 * q), &sv, &cv);
        float2 ww = make_float2(cv, sv);     // stage t+1 base twiddle
        float2 s2 = cmul(ww, ww);
        float2 w1 = cmul(s2, s2);            // ww^4 = e^{TP*j/(4q)}
        float2 w2 = cmul(w1, w1);
        float2 w3 = cmul(w2, w1);

        // ---- stage t: butterflies (4m..4m+3), twiddle w1^n ----
#pragma unroll
        for (int m = 0; m < 4; ++m) {
            float2 a0 = x[4 * m], a1 = x[4 * m + 1], a2 = x[4 * m + 2], a3 = x[4 * m + 3];
            a1 = cmul(a1, w1); a2 = cmul(a2, w2); a3 = cmul(a3, w3);
            float2 u0 = make_float2(a0.x + a2.x, a0.y + a2.y);
            float2 u1 = make_float2(a0.x - a2.x, a0.y - a2.y);
            float2 u2 = make_float2(a1.x + a3.x, a1.y + a3.y);
            float2 u3 = make_float2(a1.x - a3.x, a1.y - a3.y);
            x[4 * m]     = make_float2(u0.x + u2.x, u0.y + u2.y);
            x[4 * m + 2] = make_float2(u0.x - u2.x, u0.y - u2.y);
            if (SIGN < 0) {
                x[4 * m + 1] = make_float2(u1.x + u3.y, u1.y - u3.x);
                x[4 * m + 3] = make_float2(u1.x - u3.y, u1.y + u3.x);
            } else {
                x[4 * m + 1] = make_float2(u1.x - u3.y, u1.y + u3.x);
                x[4 * m + 3] = make_float2(u1.x + u3.y, u1.y - u3.x);
            }
        }

        // ---- stage t+1: butterflies (n, n+4, n+8, n+12), twiddle (ww*r16^n)^m ----
#pragma unroll
        for (int n = 0; n < 4; ++n) {
            float2 a0 = x[n], a1 = x[n + 4], a2 = x[n + 8], a3 = x[n + 12];
            {
                float2 r = make_float2(R16C[n], (SIGN < 0) ? -R16S[n] : R16S[n]);
                float2 wp = (n > 0) ? cmul(ww, r) : ww;
                float2 wp2 = cmul(wp, wp);
                float2 wp3 = cmul(wp2, wp);
                a1 = cmul(a1, wp);
                a2 = cmul(a2, wp2);
                a3 = cmul(a3, wp3);
            }
            float2 u0 = make_float2(a0.x + a2.x, a0.y + a2.y);
            float2 u1 = make_float2(a0.x - a2.x, a0.y - a2.y);
            float2 u2 = make_float2(a1.x + a3.x, a1.y + a3.y);
            float2 u3 = make_float2(a1.x - a3.x, a1.y - a3.y);
            x[n]      = make_float2(u0.x + u2.x, u0.y + u2.y);
            x[n + 8]  = make_float2(u0.x - u2.x, u0.y - u2.y);
            if (SIGN < 0) {
                x[n + 4]  = make_float2(u1.x + u3.y, u1.y - u3.x);
                x[n + 12] = make_float2(u1.x - u3.y, u1.y + u3.x);
            } else {
                x[n + 4]  = make_float2(u1.x - u3.y, u1.y + u3.x);
                x[n + 12] = make_float2(u1.x + u3.y, u1.y - u3.x);
            }
        }
#pragma unroll
        for (int l = 0; l < 16; ++l) lds[ldsIdx(base + l * q)] = x[l];
        __syncthreads();
    }
}

// z-pair: given per-stem A[k] (=a), A[M-k] (=bb), w = e^{-2pi*i*k/NS},
// produce packed-inverse inputs Z'[k] (=z1), Z'[M-k] (=z2). LINEAR in (a,bb),
// so per-stem zpair then summing over events == summing then zpair.
__device__ __forceinline__ void zpair(float2 a, float2 bb, float2 w,
                                      float2* z1, float2* z2) {
    float2 E1 = make_float2(0.5f * (a.x + bb.x), 0.5f * (a.y - bb.y));
    float2 D1 = make_float2(0.5f * (a.x - bb.x), 0.5f * (a.y + bb.y));
    float2 O1 = cmul(make_float2(w.x, -w.y), D1);
    *z1 = make_float2(E1.x - O1.y, E1.y + O1.x);          // E1 + i*O1
    float2 D2 = make_float2(-D1.x, D1.y);                  // -conj(D1)
    float2 O2p = cmul(w, D2);                              // O2 = -O2p
    *z2 = make_float2(E1.x + O2p.y, -E1.y - O2p.x);        // conj(E1) + i*O2
}

// Kernel A: one block per (b,e). Wave 0 computes the shift (pos folded in).
// Load+stage0+scatter -> stage pairs -> unpack HALF-SPECTRUM (k=0..M/2):
// from (Zk, Zr) get BOTH X[k]=E+wo and X[M-k]=conj(E-wo); phase both
// (ph(M-k) = e^{-i*pi*s} * conj(ph(k)), exact si-parity); zpair -> write the
// per-stem PACKED inverse-FFT input Z'_e row in natural order.
// reduce then is a pure elementwise sum and inv needs no repack.
__global__ __launch_bounds__(T2, 4) void fft_phase_kernel(float* __restrict__ stems,
                                                          const float* __restrict__ tl,
                                                          const float* __restrict__ W,
                                                          const float* __restrict__ bp) {
    __shared__ float2 lds[LDS_ELEMS];
    __shared__ float sh_shift;
    const int tid = threadIdx.x;
    const int row = blockIdx.x;
    float* rowp = stems + (size_t)row * NS;

    if (tid < 64) {   // wave 0: pos = sigmoid(dot(tl,W)+b) * NS
        const float* trow = tl + (size_t)row * 128;
        float p = trow[tid] * W[tid] + trow[tid + 64] * W[tid + 64];
#pragma unroll
        for (int off = 32; off > 0; off >>= 1) p += __shfl_down(p, off);
        if (tid == 0) {
            float x = p + bp[0];
            sh_shift = (1.0f / (1.0f + expf(-x))) * (float)NS;
        }
    }

    load_stage0_scatter<-1>((const float4*)rowp, lds, tid);
    __syncthreads();
    fft_pairs<-1>(lds, tid);

    const float s = sh_shift;
    const int si = (int)floorf(s);
    const float sf = s - (float)si;
    float2* spec = (float2*)rowp;

    // phM = e^{-i*pi*s} exactly: (-1)^si * e^{-i*pi*sf}
    float msv, mcv;
    __sincosf(-3.14159265358979323846f * sf, &msv, &mcv);
    float2 phM = make_float2(mcv, msv);
    if (si & 1) { phM.x = -phM.x; phM.y = -phM.y; }

    const float2 ph0 = shift_phase(tid, si, sf);   // e^{-i*2pi*tid*s/NS}
    const float2 w0  = wNS(tid);                   // e^{-i*2pi*tid/NS}
    const float2 q1  = shift_phase(1024, si, sf);  // e^{-i*2pi*1024*s/NS}
    const float2 q2  = cmul(q1, q1);
    const float2 q3  = cmul(q2, q1);
    const float2 q4  = cmul(q2, q2);
    float2 phb = ph0;
#pragma unroll
    for (int t = 0; t < 8; ++t) {                  // k = 0..8191 (+ partners)
        int k = tid + (t << 10);
        float2 ph;
        switch (t & 3) {
            case 0:  ph = phb; break;
            case 1:  ph = cmul(phb, q1); break;
            case 2:  ph = cmul(phb, q2); break;
            default: ph = cmul(phb, q3); break;
        }
        if (k == 0) {
            // slot 0: Z'[0] = ((DC+Nq)/2, (DC-Nq)/2), Nq = X[M]*cos(pi*s)
            float2 z0 = lds[ldsIdx(0)];
            float X0 = z0.x + z0.y;
            float XM = z0.x - z0.y;
            float Nq = XM * phM.x;
            spec[0] = make_float2(0.5f * (X0 + Nq), 0.5f * (X0 - Nq));
            // self-paired slot M/2: X[M/2] = conj(Z[M/2]); Z'[M/2] = conj(A[M/2])
            float2 Zh = lds[ldsIdx(M / 2)];
            float2 Xh = make_float2(Zh.x, -Zh.y);
            float2 ph_h = shift_phase(M / 2, si, sf);
            float2 Ah = cmul(Xh, ph_h);
            spec[M / 2] = make_float2(Ah.x, -Ah.y);
        } else {
            float2 Zk = lds[ldsIdx(k)];
            float2 Zr = lds[ldsIdx(M - k)];
            float2 E = make_float2(0.5f * (Zk.x + Zr.x), 0.5f * (Zk.y - Zr.y));
            float2 O = make_float2(0.5f * (Zk.y + Zr.y), -0.5f * (Zk.x - Zr.x));
            float2 w = cmul(w0, make_float2(C32[t], -S32[t]));   // wNS(k)
            float2 wo = cmul(w, O);
            float2 Xk = make_float2(E.x + wo.x, E.y + wo.y);     // X[k]
            float2 Xm = make_float2(E.x - wo.x, wo.y - E.y);     // conj(E-wo)=X[M-k]
            float2 Ak = cmul(Xk, ph);
            float2 phm = cmul(phM, make_float2(ph.x, -ph.y));    // ph(M-k)
            float2 Am = cmul(Xm, phm);
            float2 z1, z2;
            zpair(Ak, Am, w, &z1, &z2);
            spec[k] = z1;
            spec[M - k] = z2;
        }
        if ((t & 3) == 3) phb = cmul(phb, q4);
    }
}

// Kernel B: pure elementwise sum of the 16 per-stem packed Z' rows per batch.
// Writes the batch's packed spectrum into d_out (8 MB, exactly out_size).
__global__ __launch_bounds__(256) void reduce_kernel(const float4* __restrict__ stems,
                                                     float4* __restrict__ out) {
    int gid = blockIdx.x * 256 + threadIdx.x;   // 0 .. NB*NS/4-1
    int b = gid >> 13;                           // / (NS/4)
    int i = gid & (NS / 4 - 1);
    const float4* base = stems + (size_t)b * NEV * (NS / 4) + i;
    float4 s = base[0];
#pragma unroll
    for (int e = 1; e < NEV; ++e) {
        float4 v = base[(size_t)e * (NS / 4)];
        s.x += v.x; s.y += v.y; s.z += v.z; s.w += v.w;
    }
    out[gid] = s;
}

// Kernel C: one block per batch. Z' is already packed & natural-order in
// d_out: fused load+stage0+scatter -> inverse stage pairs -> scaled real write.
__global__ __launch_bounds__(T2, 4) void inv_kernel(float* __restrict__ out) {
    __shared__ float2 lds[LDS_ELEMS];
    const int tid = threadIdx.x;
    const int b = blockIdx.x;
    float* rowp = out + (size_t)b * NS;

    load_stage0_scatter<1>((const float4*)rowp, lds, tid);
    __syncthreads();
    fft_pairs<1>(lds, tid);

    const float invM = 1.0f / (float)M;
    float4* dst = (float4*)rowp;
#pragma unroll
    for (int it = 0; it < (NS / 4) / T2; ++it) {
        int i = tid + it * T2;
        float2 z0 = lds[ldsIdx(2 * i)];
        float2 z1 = lds[ldsIdx(2 * i + 1)];
        dst[i] = make_float4(z0.x * invM, z0.y * invM, z1.x * invM, z1.y * invM);
    }
}

extern "C" void kernel_launch(void* const* d_in, const int* in_sizes, int n_in,
                              void* d_out, int out_size, void* d_ws, size_t ws_size,
                              hipStream_t stream) {
    const float* time_latent = (const float*)d_in[0];
    float* stems = (float*)d_in[1];  // clobbered in place; harness restores per launch
    // d_in[2] = targets: unused by the reference output
    const float* W_pos = (const float*)d_in[3];
    const float* b_pos = (const float*)d_in[4];
    float* out = (float*)d_out;

    fft_phase_kernel<<<NB * NEV, T2, 0, stream>>>(stems, time_latent, W_pos, b_pos);
    reduce_kernel<<<(NB * NS / 4) / 256, 256, 0, stream>>>((const float4*)stems,
                                                           (float4*)out);
    inv_kernel<<<NB, T2, 0, stream>>>(out);
}